// Round 3
// baseline (505.167 us; speedup 1.0000x reference)
//
#include <hip/hip_runtime.h>
#include <math.h>

#define BATCH 8
#define NN    2048
#define FIN   512
#define FOUT  256
#define NEG_BIG -9000000000000000.0f

// ---------------------------------------------------------------------------
// Kernel 1: h = x @ W   (M = B*N = 16384, K = 512, Nc = 256)
// 128x64 tile, BK=16, 256 threads, 8x4 acc per thread. A staged transposed.
// ---------------------------------------------------------------------------
__global__ __launch_bounds__(256) void gemm_xw(const float* __restrict__ x,
                                               const float* __restrict__ W,
                                               float* __restrict__ h) {
    __shared__ float As[16][128];   // [k][m]
    __shared__ float Bs[16][68];    // [k][n] padded (272B row = 17*16, stays 16B aligned)
    const int t  = threadIdx.x;
    const int m0 = (blockIdx.x >> 2) * 128;
    const int n0 = (blockIdx.x & 3) * 64;
    const int ty = t >> 4, tx = t & 15;     // ty: row group (8 rows), tx: col group (4 cols)
    const int lrow = t & 127;               // A-load row
    const int lk8  = (t >> 7) * 8;          // A-load k offset (0 or 8)
    const int bk = t >> 4;                  // B-load k (0..15)
    const int bc = (t & 15) * 4;            // B-load col*4
    float acc[8][4] = {};

    for (int k0 = 0; k0 < FIN; k0 += 16) {
        const float4* xa = (const float4*)(x + (size_t)(m0 + lrow) * FIN + k0 + lk8);
        float4 a0 = xa[0];
        float4 a1 = xa[1];
        float4 bv = *(const float4*)(W + (size_t)(k0 + bk) * FOUT + n0 + bc);
        __syncthreads();   // previous iteration's reads done before overwrite
        As[lk8+0][lrow]=a0.x; As[lk8+1][lrow]=a0.y; As[lk8+2][lrow]=a0.z; As[lk8+3][lrow]=a0.w;
        As[lk8+4][lrow]=a1.x; As[lk8+5][lrow]=a1.y; As[lk8+6][lrow]=a1.z; As[lk8+7][lrow]=a1.w;
        *(float4*)&Bs[bk][bc] = bv;
        __syncthreads();
        #pragma unroll
        for (int kk = 0; kk < 16; kk++) {
            float4 af0 = *(const float4*)&As[kk][ty*8];
            float4 af1 = *(const float4*)&As[kk][ty*8+4];
            float4 bf  = *(const float4*)&Bs[kk][tx*4];
            float av[8]  = {af0.x,af0.y,af0.z,af0.w,af1.x,af1.y,af1.z,af1.w};
            float bvv[4] = {bf.x,bf.y,bf.z,bf.w};
            #pragma unroll
            for (int i = 0; i < 8; i++)
                #pragma unroll
                for (int j = 0; j < 4; j++)
                    acc[i][j] = fmaf(av[i], bvv[j], acc[i][j]);
        }
    }
    #pragma unroll
    for (int i = 0; i < 8; i++) {
        float4 v = make_float4(acc[i][0], acc[i][1], acc[i][2], acc[i][3]);
        *(float4*)(h + (size_t)(m0 + ty*8 + i) * FOUT + n0 + tx*4) = v;
    }
}

// ---------------------------------------------------------------------------
// Kernel 2: f = h@a1, g = h@a2. One wave per row (64 lanes * float4 = 256).
// ---------------------------------------------------------------------------
__global__ __launch_bounds__(256) void fg_kernel(const float* __restrict__ h,
                                                 const float* __restrict__ a,
                                                 float* __restrict__ f,
                                                 float* __restrict__ g) {
    const int wave = threadIdx.x >> 6;
    const int lane = threadIdx.x & 63;
    const int row  = blockIdx.x * 4 + wave;          // 16384 rows / 4096 blocks
    const float4 hv = *(const float4*)(h + (size_t)row * FOUT + lane * 4);
    const float4 a1 = *(const float4*)(a + lane * 4);
    const float4 a2 = *(const float4*)(a + FOUT + lane * 4);
    float fs = hv.x*a1.x + hv.y*a1.y + hv.z*a1.z + hv.w*a1.w;
    float gs = hv.x*a2.x + hv.y*a2.y + hv.z*a2.z + hv.w*a2.w;
    #pragma unroll
    for (int m = 1; m < 64; m <<= 1) {
        fs += __shfl_xor(fs, m);
        gs += __shfl_xor(gs, m);
    }
    if (lane == 0) { f[row] = fs; g[row] = gs; }
}

// ---------------------------------------------------------------------------
// Kernel 3: fused masked-softmax attention + PV + ELU.
// Block: batch b = blockIdx%8 (XCD-aligned so h[b] (2MB) stays in one XCD L2),
// 32 query rows (i0..i0+31), 256 threads, online softmax over 64 j-tiles of 32.
// Phase A: scores+softmax state (thread = (i, 4 j's)); Phase B: PV FMA
// (thread = 4 rows x 8 cols register tile; h-tile + p-tile from LDS).
// ---------------------------------------------------------------------------
__global__ __launch_bounds__(256, 2) void gat_attn(const float* __restrict__ h,
                                                   const int* __restrict__ adj,
                                                   const float* __restrict__ f,
                                                   const float* __restrict__ g,
                                                   float* __restrict__ out) {
    const int b  = blockIdx.x & 7;
    const int it = blockIdx.x >> 3;     // 0..63
    const int i0 = it * 32;
    const int t  = threadIdx.x;

    __shared__ float Hs[32][256];       // h j-tile  [j][o]  (32 KB, contiguous copy)
    __shared__ float Ps[32][36];        // p         [j][i]  (row = 144B, 16B aligned)
    __shared__ float m_s[32], l_s[32], fac_s[32];

    // phase A identity
    const int ai = t >> 3;              // row 0..31
    const int jq = t & 7;               // j quarter (4 j's each)
    const float fi = f[(size_t)b * NN + i0 + ai];
    // phase B identity
    const int ib = t >> 5;              // row group 0..7 (4 rows)
    const int ob = t & 31;              // col group (8 cols)

    if (t < 32) { m_s[t] = -INFINITY; l_s[t] = 0.0f; }

    float acc[4][8] = {};
    const float* hb = h + ((size_t)b * NN) * FOUT;

    for (int tile = 0; tile < 64; tile++) {
        const int j0 = tile * 32;
        __syncthreads();   // prev phase B done with Hs/Ps; init visible on tile 0

        // ---- stage Hs: contiguous 32KB block of h[b][j0..j0+32][:] ----
        {
            const float4* src = (const float4*)(hb + (size_t)j0 * FOUT);
            float4* dst = (float4*)Hs;
            #pragma unroll
            for (int r = 0; r < 8; r++) dst[t + 256*r] = src[t + 256*r];
        }

        // ---- phase A: scores, online-softmax state, write Ps ----
        {
            const int4 av = *(const int4*)(adj + ((size_t)b * NN + i0 + ai) * NN + j0 + jq*4);
            const float4 gv = *(const float4*)(g + (size_t)b * NN + j0 + jq*4);
            float s[4];
            {
                float v0 = fi + gv.x, v1 = fi + gv.y, v2 = fi + gv.z, v3 = fi + gv.w;
                s[0] = av.x > 0 ? (v0 > 0.f ? v0 : 0.2f*v0) : NEG_BIG;
                s[1] = av.y > 0 ? (v1 > 0.f ? v1 : 0.2f*v1) : NEG_BIG;
                s[2] = av.z > 0 ? (v2 > 0.f ? v2 : 0.2f*v2) : NEG_BIG;
                s[3] = av.w > 0 ? (v3 > 0.f ? v3 : 0.2f*v3) : NEG_BIG;
            }
            float mloc = fmaxf(fmaxf(s[0], s[1]), fmaxf(s[2], s[3]));
            mloc = fmaxf(mloc, __shfl_xor(mloc, 1));
            mloc = fmaxf(mloc, __shfl_xor(mloc, 2));
            mloc = fmaxf(mloc, __shfl_xor(mloc, 4));
            const float m_old = m_s[ai];                 // wave-synchronous read
            const float m_new = fmaxf(m_old, mloc);      // >= NEG_BIG, always finite
            float p[4], rs = 0.f;
            #pragma unroll
            for (int e = 0; e < 4; e++) { p[e] = expf(s[e] - m_new); rs += p[e]; }
            rs += __shfl_xor(rs, 1);
            rs += __shfl_xor(rs, 2);
            rs += __shfl_xor(rs, 4);
            if (jq == 0) {
                const float fac = expf(m_old - m_new);   // exp(-inf - finite) = 0 on tile 0
                fac_s[ai] = fac;
                l_s[ai] = l_s[ai] * fac + rs;
                m_s[ai] = m_new;
            }
            Ps[jq*4+0][ai] = p[0];
            Ps[jq*4+1][ai] = p[1];
            Ps[jq*4+2][ai] = p[2];
            Ps[jq*4+3][ai] = p[3];
        }
        __syncthreads();

        // ---- phase B: rescale + PV accumulate ----
        {
            float fac[4];
            #pragma unroll
            for (int r = 0; r < 4; r++) fac[r] = fac_s[ib*4 + r];
            #pragma unroll
            for (int r = 0; r < 4; r++)
                #pragma unroll
                for (int c = 0; c < 8; c++) acc[r][c] *= fac[r];
            #pragma unroll 4
            for (int j = 0; j < 32; j++) {
                const float4 pv = *(const float4*)&Ps[j][ib*4];
                const float4 h0 = *(const float4*)&Hs[j][ob*8];
                const float4 h1 = *(const float4*)&Hs[j][ob*8+4];
                const float pr[4] = {pv.x, pv.y, pv.z, pv.w};
                const float hc[8] = {h0.x,h0.y,h0.z,h0.w,h1.x,h1.y,h1.z,h1.w};
                #pragma unroll
                for (int r = 0; r < 4; r++)
                    #pragma unroll
                    for (int c = 0; c < 8; c++)
                        acc[r][c] = fmaf(pr[r], hc[c], acc[r][c]);
            }
        }
    }

    // ---- epilogue: normalize + ELU + store ----
    #pragma unroll
    for (int r = 0; r < 4; r++) {
        const float inv = 1.0f / l_s[ib*4 + r];
        float o[8];
        #pragma unroll
        for (int c = 0; c < 8; c++) {
            float v = acc[r][c] * inv;
            o[c] = v > 0.f ? v : expm1f(v);
        }
        float* op = out + ((size_t)b * NN + i0 + ib*4 + r) * FOUT + ob*8;
        *(float4*)op     = make_float4(o[0], o[1], o[2], o[3]);
        *(float4*)(op+4) = make_float4(o[4], o[5], o[6], o[7]);
    }
}

// ---------------------------------------------------------------------------
extern "C" void kernel_launch(void* const* d_in, const int* in_sizes, int n_in,
                              void* d_out, int out_size, void* d_ws, size_t ws_size,
                              hipStream_t stream) {
    const float* x   = (const float*)d_in[0];   // (8, 2048, 512)
    const int*   adj = (const int*)  d_in[1];   // (8, 2048, 2048)
    const float* W   = (const float*)d_in[2];   // (512, 256)
    const float* a   = (const float*)d_in[3];   // (512, 1)
    float* outp = (float*)d_out;                // (8, 2048, 256)

    float* h = (float*)d_ws;                    // 4,194,304 floats (16 MB)
    float* f = h + (size_t)BATCH * NN * FOUT;   // 16384 floats
    float* g = f + (size_t)BATCH * NN;          // 16384 floats

    gemm_xw <<<512, 256, 0, stream>>>(x, W, h);
    fg_kernel<<<4096, 256, 0, stream>>>(h, a, f, g);
    gat_attn<<<512, 256, 0, stream>>>(h, adj, f, g, outp);
}

// Round 5
// 354.495 us; speedup vs baseline: 1.4250x; 1.4250x over previous
//
#include <hip/hip_runtime.h>
#include <math.h>

#define BATCH 8
#define NN    2048
#define FIN   512
#define FOUT  256
#define NEG_BIG -9000000000000000.0f

typedef __attribute__((ext_vector_type(8))) short bf16x8;   // 8 bf16 in 4 VGPR
typedef __attribute__((ext_vector_type(4))) float f32x4;    // MFMA accumulator

// round-to-nearest-even fp32 -> bf16 (inputs never NaN here)
__device__ __forceinline__ unsigned short f2bf(float x) {
    unsigned u = __float_as_uint(x);
    u = (u + 0x7FFF + ((u >> 16) & 1)) >> 16;
    return (unsigned short)u;
}
__device__ __forceinline__ float bf2f(unsigned short h) {
    return __uint_as_float(((unsigned)h) << 16);
}

// ---------------------------------------------------------------------------
// Kernel 0: Wt_hi/Wt_lo[n][k] = split-bf16 of W[k][n] (transposed, frag-friendly)
// ---------------------------------------------------------------------------
__global__ __launch_bounds__(256) void wt_prep(const float* __restrict__ W,
                                               unsigned short* __restrict__ Wt_hi,
                                               unsigned short* __restrict__ Wt_lo) {
    const int tg = blockIdx.x * 256 + threadIdx.x;   // 32768 threads
    const int n  = tg >> 7;                          // 0..255
    const int k4 = (tg & 127) * 4;                   // 0..508
    unsigned short h[4], lo[4];
    #pragma unroll
    for (int i = 0; i < 4; i++) {
        const float v = W[(size_t)(k4 + i) * FOUT + n];
        h[i]  = f2bf(v);
        lo[i] = f2bf(v - bf2f(h[i]));
    }
    uint2 ph, pl;
    ph.x = h[0]  | ((unsigned)h[1]  << 16); ph.y = h[2]  | ((unsigned)h[3]  << 16);
    pl.x = lo[0] | ((unsigned)lo[1] << 16); pl.y = lo[2] | ((unsigned)lo[3] << 16);
    *(uint2*)(Wt_hi + (size_t)n * FIN + k4) = ph;
    *(uint2*)(Wt_lo + (size_t)n * FIN + k4) = pl;
}

// ---------------------------------------------------------------------------
// Kernel 1: ht = (x @ W)^T per batch, split-bf16 out.  MFMA 16x16x32 bf16,
// 3-product split: xhi*Whi + xhi*Wlo + xlo*Whi (fp32-level accuracy).
// Block 256 th = 4 waves; tile BM=128 x BN=64; wave = 64x32 (mt4 x nt2); BK=32.
// A (x) staged in LDS as bf16 hi/lo, pad row to 40 shorts (80B, 16B-aligned).
// B frags read from precomputed Wt (L1/L2 resident, 512KB).
// C written transposed: ht[b][n][j], 4 consecutive j per lane (8B stores).
// ---------------------------------------------------------------------------
__global__ __launch_bounds__(256, 2) void gemm_xw(const float* __restrict__ x,
        const unsigned short* __restrict__ Wt_hi,
        const unsigned short* __restrict__ Wt_lo,
        unsigned short* __restrict__ ht_hi,
        unsigned short* __restrict__ ht_lo) {
    __shared__ unsigned short As_hi[128][40];
    __shared__ unsigned short As_lo[128][40];
    const int t  = threadIdx.x;
    const int m0 = (blockIdx.x >> 2) * 128;
    const int n0 = (blockIdx.x & 3) * 64;
    const int l  = t & 63, w = t >> 6;
    const int wr = w >> 1, wc = w & 1;      // wave grid 2x2
    const int lr = l & 15, lk = l >> 4;     // frag row / k-group

    f32x4 acc[4][2];
    #pragma unroll
    for (int mt = 0; mt < 4; mt++)
        #pragma unroll
        for (int nt = 0; nt < 2; nt++) acc[mt][nt] = (f32x4){0.f,0.f,0.f,0.f};

    for (int k0 = 0; k0 < FIN; k0 += 32) {
        // load x tile 128x32 (coalesced float4)
        float4 xv[4];
        #pragma unroll
        for (int r = 0; r < 4; r++) {
            const int fidx = t + 256*r, m = fidx >> 3, kq = fidx & 7;
            xv[r] = *(const float4*)(x + (size_t)(m0 + m) * FIN + k0 + kq*4);
        }
        // B frags from global Wt (no LDS dependency — issue early)
        bf16x8 bh[2], bl[2];
        #pragma unroll
        for (int nt = 0; nt < 2; nt++) {
            const size_t off = (size_t)(n0 + wc*32 + nt*16 + lr) * FIN + k0 + lk*8;
            bh[nt] = *(const bf16x8*)(Wt_hi + off);
            bl[nt] = *(const bf16x8*)(Wt_lo + off);
        }
        __syncthreads();   // prev iter's frag reads done
        #pragma unroll
        for (int r = 0; r < 4; r++) {
            const int fidx = t + 256*r, m = fidx >> 3, kq = fidx & 7;
            const float vv[4] = {xv[r].x, xv[r].y, xv[r].z, xv[r].w};
            unsigned short h[4], lo[4];
            #pragma unroll
            for (int i = 0; i < 4; i++) { h[i] = f2bf(vv[i]); lo[i] = f2bf(vv[i] - bf2f(h[i])); }
            uint2 ph, pl;
            ph.x = h[0]  | ((unsigned)h[1]  << 16); ph.y = h[2]  | ((unsigned)h[3]  << 16);
            pl.x = lo[0] | ((unsigned)lo[1] << 16); pl.y = lo[2] | ((unsigned)lo[3] << 16);
            *(uint2*)&As_hi[m][kq*4] = ph;
            *(uint2*)&As_lo[m][kq*4] = pl;
        }
        __syncthreads();
        // A frags
        bf16x8 ah[4], al[4];
        #pragma unroll
        for (int mt = 0; mt < 4; mt++) {
            const int row = wr*64 + mt*16 + lr;
            ah[mt] = *(const bf16x8*)&As_hi[row][lk*8];
            al[mt] = *(const bf16x8*)&As_lo[row][lk*8];
        }
        #pragma unroll
        for (int nt = 0; nt < 2; nt++)
            #pragma unroll
            for (int mt = 0; mt < 4; mt++)
                acc[mt][nt] = __builtin_amdgcn_mfma_f32_16x16x32_bf16(ah[mt], bh[nt], acc[mt][nt], 0, 0, 0);
        #pragma unroll
        for (int nt = 0; nt < 2; nt++)
            #pragma unroll
            for (int mt = 0; mt < 4; mt++)
                acc[mt][nt] = __builtin_amdgcn_mfma_f32_16x16x32_bf16(ah[mt], bl[nt], acc[mt][nt], 0, 0, 0);
        #pragma unroll
        for (int nt = 0; nt < 2; nt++)
            #pragma unroll
            for (int mt = 0; mt < 4; mt++)
                acc[mt][nt] = __builtin_amdgcn_mfma_f32_16x16x32_bf16(al[mt], bh[nt], acc[mt][nt], 0, 0, 0);
    }

    // epilogue: C/D layout col=lane&15, row=(lane>>4)*4+reg  [m89-verified]
    #pragma unroll
    for (int mt = 0; mt < 4; mt++)
        #pragma unroll
        for (int nt = 0; nt < 2; nt++) {
            const int n  = n0 + wc*32 + nt*16 + lr;
            const int mb = m0 + wr*64 + mt*16 + lk*4;
            const int bb = mb >> 11, jj = mb & 2047;
            const float av[4] = {acc[mt][nt].x, acc[mt][nt].y, acc[mt][nt].z, acc[mt][nt].w};
            unsigned short h[4], lo[4];
            #pragma unroll
            for (int r = 0; r < 4; r++) { h[r] = f2bf(av[r]); lo[r] = f2bf(av[r] - bf2f(h[r])); }
            uint2 ph, pl;
            ph.x = h[0]  | ((unsigned)h[1]  << 16); ph.y = h[2]  | ((unsigned)h[3]  << 16);
            pl.x = lo[0] | ((unsigned)lo[1] << 16); pl.y = lo[2] | ((unsigned)lo[3] << 16);
            const size_t base = ((size_t)bb * FOUT + n) * NN + jj;
            *(uint2*)(ht_hi + base) = ph;
            *(uint2*)(ht_lo + base) = pl;
        }
}

// ---------------------------------------------------------------------------
// Kernel 2: f = h@a1, g = h@a2 from split ht. Wave per 64-j chunk, loop n.
// ---------------------------------------------------------------------------
__global__ __launch_bounds__(256) void fg2(const unsigned short* __restrict__ ht_hi,
                                           const unsigned short* __restrict__ ht_lo,
                                           const float* __restrict__ a,
                                           float* __restrict__ f, float* __restrict__ g) {
    const int lane  = threadIdx.x & 63;
    const int chunk = blockIdx.x * 4 + (threadIdx.x >> 6);   // 0..255
    const int b  = chunk >> 5;
    const int jw = (chunk & 31) * 64 + lane;
    const size_t base = (size_t)b * FOUT * NN + jw;
    float fs = 0.f, gs = 0.f;
    #pragma unroll 4
    for (int n = 0; n < FOUT; n++) {
        const float hv = bf2f(ht_hi[base + (size_t)n * NN]) + bf2f(ht_lo[base + (size_t)n * NN]);
        fs = fmaf(hv, a[n], fs);
        gs = fmaf(hv, a[FOUT + n], gs);
    }
    f[b * NN + jw] = fs;
    g[b * NN + jw] = gs;
}

// ---------------------------------------------------------------------------
// Kernel 3: fused masked-softmax attention + PV (MFMA) + ELU.
// Block = 64 i-rows x 256 cols, 4 waves (wave = 64x64, mt4 x nt4), KVBLK=64.
// Grid 256; blockIdx&7 = batch (XCD-L2 locality for ht).
// Phase A (VALU fp32): scores from rank-1 f_i+g_j, adj mask, online softmax;
// writes P as split-bf16 to LDS. Phase B: rescale acc, 96 MFMA (3-product).
// LDS rows padded to 72 shorts (144B, 16B-aligned).
// ---------------------------------------------------------------------------
__global__ __launch_bounds__(256, 1) void gat_attn(
        const unsigned short* __restrict__ ht_hi,
        const unsigned short* __restrict__ ht_lo,
        const int* __restrict__ adj,
        const float* __restrict__ f, const float* __restrict__ g,
        float* __restrict__ out) {
    __shared__ unsigned short Hs_hi[256][72];
    __shared__ unsigned short Hs_lo[256][72];
    __shared__ unsigned short Ps_hi[64][72];
    __shared__ unsigned short Ps_lo[64][72];
    __shared__ __attribute__((aligned(16))) float m_s[64];
    __shared__ __attribute__((aligned(16))) float l_s[64];
    __shared__ __attribute__((aligned(16))) float fac_s[64];

    const int b  = blockIdx.x & 7;
    const int i0 = (blockIdx.x >> 3) * 64;
    const int t  = threadIdx.x;
    const int w  = t >> 6, l = t & 63;
    const int lr = l & 15, lk = l >> 4;
    // phase A identity: 64 rows x 4 j-groups of 16
    const int ar = t >> 2, jg = t & 3;
    const float fi = f[b * NN + i0 + ar];

    if (t < 64) { m_s[t] = -INFINITY; l_s[t] = 0.f; }

    f32x4 acc[4][4];
    #pragma unroll
    for (int mt = 0; mt < 4; mt++)
        #pragma unroll
        for (int nt = 0; nt < 4; nt++) acc[mt][nt] = (f32x4){0.f,0.f,0.f,0.f};

    const unsigned short* hb_hi = ht_hi + (size_t)b * FOUT * NN;
    const unsigned short* hb_lo = ht_lo + (size_t)b * FOUT * NN;

    for (int jt = 0; jt < 32; jt++) {
        const int j0 = jt * 64;
        __syncthreads();   // init visible / prev MFMA done with Hs,Ps,fac

        // ---- stage ht j-tile [256 n][64 j] hi+lo into LDS ----
        {
            const int sn = t >> 3, sp = t & 7;   // 8 lanes x 16B cover one row's 128B
            #pragma unroll
            for (int p8 = 0; p8 < 8; p8++) {
                const int n = sn + p8 * 32;
                const size_t goff = (size_t)n * NN + j0 + sp * 8;
                const uint4 vh = *(const uint4*)(hb_hi + goff);
                const uint4 vl = *(const uint4*)(hb_lo + goff);
                *(uint4*)&Hs_hi[n][sp * 8] = vh;
                *(uint4*)&Hs_lo[n][sp * 8] = vl;
            }
        }

        // ---- phase A: scores + online softmax + P split-bf16 ----
        {
            float s[16];
            float mloc = -INFINITY;
            const size_t arow = ((size_t)b * NN + i0 + ar) * NN + j0 + jg * 16;
            #pragma unroll
            for (int c = 0; c < 4; c++) {
                const int4   av = *(const int4*)(adj + arow + c * 4);
                const float4 gv = *(const float4*)(g + b * NN + j0 + jg * 16 + c * 4);
                const float v0 = fi + gv.x, v1 = fi + gv.y, v2 = fi + gv.z, v3 = fi + gv.w;
                s[c*4+0] = av.x > 0 ? (v0 > 0.f ? v0 : 0.2f * v0) : NEG_BIG;
                s[c*4+1] = av.y > 0 ? (v1 > 0.f ? v1 : 0.2f * v1) : NEG_BIG;
                s[c*4+2] = av.z > 0 ? (v2 > 0.f ? v2 : 0.2f * v2) : NEG_BIG;
                s[c*4+3] = av.w > 0 ? (v3 > 0.f ? v3 : 0.2f * v3) : NEG_BIG;
            }
            #pragma unroll
            for (int e = 0; e < 16; e++) mloc = fmaxf(mloc, s[e]);
            mloc = fmaxf(mloc, __shfl_xor(mloc, 1));
            mloc = fmaxf(mloc, __shfl_xor(mloc, 2));
            const float m_old = m_s[ar];           // row group = 4 lanes, same wave
            const float m_new = fmaxf(m_old, mloc);
            float p[16], rs = 0.f;
            #pragma unroll
            for (int e = 0; e < 16; e++) { p[e] = __expf(s[e] - m_new); rs += p[e]; }
            rs += __shfl_xor(rs, 1);
            rs += __shfl_xor(rs, 2);
            if (jg == 0) {
                const float fac = __expf(m_old - m_new);  // 0 on first tile
                fac_s[ar] = fac;
                l_s[ar]   = l_s[ar] * fac + rs;
                m_s[ar]   = m_new;
            }
            unsigned ph[8], pl[8];
            #pragma unroll
            for (int e = 0; e < 16; e += 2) {
                const unsigned short h0 = f2bf(p[e]),   h1 = f2bf(p[e+1]);
                const unsigned short q0 = f2bf(p[e] - bf2f(h0));
                const unsigned short q1 = f2bf(p[e+1] - bf2f(h1));
                ph[e >> 1] = h0 | ((unsigned)h1 << 16);
                pl[e >> 1] = q0 | ((unsigned)q1 << 16);
            }
            *(uint4*)&Ps_hi[ar][jg*16]     = make_uint4(ph[0], ph[1], ph[2], ph[3]);
            *(uint4*)&Ps_hi[ar][jg*16 + 8] = make_uint4(ph[4], ph[5], ph[6], ph[7]);
            *(uint4*)&Ps_lo[ar][jg*16]     = make_uint4(pl[0], pl[1], pl[2], pl[3]);
            *(uint4*)&Ps_lo[ar][jg*16 + 8] = make_uint4(pl[4], pl[5], pl[6], pl[7]);
        }
        __syncthreads();   // Hs, Ps, fac ready

        // ---- phase B: rescale + MFMA PV ----
        #pragma unroll
        for (int mt = 0; mt < 4; mt++) {
            const f32x4 fac4 = *(const f32x4*)&fac_s[mt*16 + lk*4];  // reg r <-> row
            #pragma unroll
            for (int nt = 0; nt < 4; nt++) acc[mt][nt] *= fac4;
        }
        #pragma unroll
        for (int kt = 0; kt < 2; kt++) {
            bf16x8 ah[4], al[4], bh[4], bl[4];
            #pragma unroll
            for (int mt = 0; mt < 4; mt++) {
                ah[mt] = *(const bf16x8*)&Ps_hi[mt*16 + lr][kt*32 + lk*8];
                al[mt] = *(const bf16x8*)&Ps_lo[mt*16 + lr][kt*32 + lk*8];
            }
            #pragma unroll
            for (int nt = 0; nt < 4; nt++) {
                const int n = w*64 + nt*16 + lr;
                bh[nt] = *(const bf16x8*)&Hs_hi[n][kt*32 + lk*8];
                bl[nt] = *(const bf16x8*)&Hs_lo[n][kt*32 + lk*8];
            }
            #pragma unroll
            for (int nt = 0; nt < 4; nt++)
                #pragma unroll
                for (int mt = 0; mt < 4; mt++)
                    acc[mt][nt] = __builtin_amdgcn_mfma_f32_16x16x32_bf16(ah[mt], bh[nt], acc[mt][nt], 0, 0, 0);
            #pragma unroll
            for (int nt = 0; nt < 4; nt++)
                #pragma unroll
                for (int mt = 0; mt < 4; mt++)
                    acc[mt][nt] = __builtin_amdgcn_mfma_f32_16x16x32_bf16(ah[mt], bl[nt], acc[mt][nt], 0, 0, 0);
            #pragma unroll
            for (int nt = 0; nt < 4; nt++)
                #pragma unroll
                for (int mt = 0; mt < 4; mt++)
                    acc[mt][nt] = __builtin_amdgcn_mfma_f32_16x16x32_bf16(al[mt], bh[nt], acc[mt][nt], 0, 0, 0);
        }
    }

    __syncthreads();   // l_s final, cross-wave
    #pragma unroll
    for (int mt = 0; mt < 4; mt++) {
        const f32x4 lv = *(const f32x4*)&l_s[mt*16 + lk*4];
        const float linv[4] = {1.f/lv.x, 1.f/lv.y, 1.f/lv.z, 1.f/lv.w};
        const float av0[4][4] = {
            {acc[mt][0].x, acc[mt][0].y, acc[mt][0].z, acc[mt][0].w},
            {acc[mt][1].x, acc[mt][1].y, acc[mt][1].z, acc[mt][1].w},
            {acc[mt][2].x, acc[mt][2].y, acc[mt][2].z, acc[mt][2].w},
            {acc[mt][3].x, acc[mt][3].y, acc[mt][3].z, acc[mt][3].w}};
        #pragma unroll
        for (int nt = 0; nt < 4; nt++) {
            const int n = w*64 + nt*16 + lr;
            #pragma unroll
            for (int r = 0; r < 4; r++) {
                float v = av0[nt][r] * linv[r];
                v = v > 0.f ? v : (__expf(v) - 1.f);
                out[((size_t)(b * NN + i0 + mt*16 + lk*4 + r)) * FOUT + n] = v;
            }
        }
    }
}

// ---------------------------------------------------------------------------
extern "C" void kernel_launch(void* const* d_in, const int* in_sizes, int n_in,
                              void* d_out, int out_size, void* d_ws, size_t ws_size,
                              hipStream_t stream) {
    const float* x   = (const float*)d_in[0];   // (8, 2048, 512)
    const int*   adj = (const int*)  d_in[1];   // (8, 2048, 2048)
    const float* W   = (const float*)d_in[2];   // (512, 256)
    const float* a   = (const float*)d_in[3];   // (512, 1)
    float* outp = (float*)d_out;                // (8, 2048, 256) fp32

    // workspace layout (bytes): ht_hi 8.39M | ht_lo 8.39M | Wt_hi 256K | Wt_lo 256K | f 64K | g 64K
    char* ws = (char*)d_ws;
    unsigned short* ht_hi = (unsigned short*)ws;                       ws += (size_t)BATCH*FOUT*NN*2;
    unsigned short* ht_lo = (unsigned short*)ws;                       ws += (size_t)BATCH*FOUT*NN*2;
    unsigned short* Wt_hi = (unsigned short*)ws;                       ws += (size_t)FOUT*FIN*2;
    unsigned short* Wt_lo = (unsigned short*)ws;                       ws += (size_t)FOUT*FIN*2;
    float* f = (float*)ws;                                             ws += (size_t)BATCH*NN*4;
    float* g = (float*)ws;

    wt_prep <<<128, 256, 0, stream>>>(W, Wt_hi, Wt_lo);
    gemm_xw <<<512, 256, 0, stream>>>(x, Wt_hi, Wt_lo, ht_hi, ht_lo);
    fg2     <<<64,  256, 0, stream>>>(ht_hi, ht_lo, a, f, g);
    gat_attn<<<256, 256, 0, stream>>>(ht_hi, ht_lo, adj, f, g, outp);
}

// Round 7
// 320.471 us; speedup vs baseline: 1.5763x; 1.1062x over previous
//
#include <hip/hip_runtime.h>
#include <math.h>

#define BATCH 8
#define NN    2048
#define FIN   512
#define FOUT  256
#define NEG_BIG -9000000000000000.0f

typedef __attribute__((ext_vector_type(8))) short bf16x8;   // 8 bf16 in 4 VGPR
typedef __attribute__((ext_vector_type(4))) float f32x4;    // MFMA accumulator

// round-to-nearest-even fp32 -> bf16 (inputs never NaN here)
__device__ __forceinline__ unsigned short f2bf(float x) {
    unsigned u = __float_as_uint(x);
    u = (u + 0x7FFF + ((u >> 16) & 1)) >> 16;
    return (unsigned short)u;
}
__device__ __forceinline__ float bf2f(unsigned short h) {
    return __uint_as_float(((unsigned)h) << 16);
}
// async global->LDS, 16B per lane: dest = (wave-uniform base) + lane*16
__device__ __forceinline__ void gload_lds16(const void* g, void* l) {
    __builtin_amdgcn_global_load_lds((const __attribute__((address_space(1))) void*)g,
                                     (__attribute__((address_space(3))) void*)l,
                                     16, 0, 0);
}

// ---------------------------------------------------------------------------
// Kernel 0: Wt_hi/Wt_lo[n][k] = split-bf16 of W[k][n]
// ---------------------------------------------------------------------------
__global__ __launch_bounds__(256) void wt_prep(const float* __restrict__ W,
                                               unsigned short* __restrict__ Wt_hi,
                                               unsigned short* __restrict__ Wt_lo) {
    const int tg = blockIdx.x * 256 + threadIdx.x;
    const int n  = tg >> 7;
    const int k4 = (tg & 127) * 4;
    unsigned short h[4], lo[4];
    #pragma unroll
    for (int i = 0; i < 4; i++) {
        const float v = W[(size_t)(k4 + i) * FOUT + n];
        h[i]  = f2bf(v);
        lo[i] = f2bf(v - bf2f(h[i]));
    }
    uint2 ph, pl;
    ph.x = h[0]  | ((unsigned)h[1]  << 16); ph.y = h[2]  | ((unsigned)h[3]  << 16);
    pl.x = lo[0] | ((unsigned)lo[1] << 16); pl.y = lo[2] | ((unsigned)lo[3] << 16);
    *(uint2*)(Wt_hi + (size_t)n * FIN + k4) = ph;
    *(uint2*)(Wt_lo + (size_t)n * FIN + k4) = pl;
}

// ---------------------------------------------------------------------------
// Kernel 1: ht = (x @ W)^T, split-bf16.  MFMA body as r5; LDS-transpose
// epilogue (Tr[64][136]) then fully-coalesced 256B-row stores
// (old per-lane uint2 scatter was ~8x write-amplified).
// ---------------------------------------------------------------------------
__global__ __launch_bounds__(256, 2) void gemm_xw(const float* __restrict__ x,
        const unsigned short* __restrict__ Wt_hi,
        const unsigned short* __restrict__ Wt_lo,
        unsigned short* __restrict__ ht_hi,
        unsigned short* __restrict__ ht_lo) {
    __shared__ unsigned short As_hi[128][40];
    __shared__ unsigned short As_lo[128][40];
    __shared__ __attribute__((aligned(16))) unsigned short Tr[64][136];
    const int t  = threadIdx.x;
    const int m0 = (blockIdx.x >> 2) * 128;
    const int n0 = (blockIdx.x & 3) * 64;
    const int l  = t & 63, w = t >> 6;
    const int wr = w >> 1, wc = w & 1;
    const int lr = l & 15, lk = l >> 4;

    f32x4 acc[4][2];
    #pragma unroll
    for (int mt = 0; mt < 4; mt++)
        #pragma unroll
        for (int nt = 0; nt < 2; nt++) acc[mt][nt] = (f32x4){0.f,0.f,0.f,0.f};

    for (int k0 = 0; k0 < FIN; k0 += 32) {
        float4 xv[4];
        #pragma unroll
        for (int r = 0; r < 4; r++) {
            const int fidx = t + 256*r, m = fidx >> 3, kq = fidx & 7;
            xv[r] = *(const float4*)(x + (size_t)(m0 + m) * FIN + k0 + kq*4);
        }
        bf16x8 bh[2], bl[2];
        #pragma unroll
        for (int nt = 0; nt < 2; nt++) {
            const size_t off = (size_t)(n0 + wc*32 + nt*16 + lr) * FIN + k0 + lk*8;
            bh[nt] = *(const bf16x8*)(Wt_hi + off);
            bl[nt] = *(const bf16x8*)(Wt_lo + off);
        }
        __syncthreads();
        #pragma unroll
        for (int r = 0; r < 4; r++) {
            const int fidx = t + 256*r, m = fidx >> 3, kq = fidx & 7;
            const float vv[4] = {xv[r].x, xv[r].y, xv[r].z, xv[r].w};
            unsigned short h[4], lo[4];
            #pragma unroll
            for (int i = 0; i < 4; i++) { h[i] = f2bf(vv[i]); lo[i] = f2bf(vv[i] - bf2f(h[i])); }
            uint2 ph, pl;
            ph.x = h[0]  | ((unsigned)h[1]  << 16); ph.y = h[2]  | ((unsigned)h[3]  << 16);
            pl.x = lo[0] | ((unsigned)lo[1] << 16); pl.y = lo[2] | ((unsigned)lo[3] << 16);
            *(uint2*)&As_hi[m][kq*4] = ph;
            *(uint2*)&As_lo[m][kq*4] = pl;
        }
        __syncthreads();
        bf16x8 ah[4], al[4];
        #pragma unroll
        for (int mt = 0; mt < 4; mt++) {
            const int row = wr*64 + mt*16 + lr;
            ah[mt] = *(const bf16x8*)&As_hi[row][lk*8];
            al[mt] = *(const bf16x8*)&As_lo[row][lk*8];
        }
        #pragma unroll
        for (int nt = 0; nt < 2; nt++)
            #pragma unroll
            for (int mt = 0; mt < 4; mt++)
                acc[mt][nt] = __builtin_amdgcn_mfma_f32_16x16x32_bf16(ah[mt], bh[nt], acc[mt][nt], 0, 0, 0);
        #pragma unroll
        for (int nt = 0; nt < 2; nt++)
            #pragma unroll
            for (int mt = 0; mt < 4; mt++)
                acc[mt][nt] = __builtin_amdgcn_mfma_f32_16x16x32_bf16(ah[mt], bl[nt], acc[mt][nt], 0, 0, 0);
        #pragma unroll
        for (int nt = 0; nt < 2; nt++)
            #pragma unroll
            for (int mt = 0; mt < 4; mt++)
                acc[mt][nt] = __builtin_amdgcn_mfma_f32_16x16x32_bf16(al[mt], bh[nt], acc[mt][nt], 0, 0, 0);
    }

    // ---- epilogue: LDS transpose, two passes (hi then lo), coalesced stores
    const int bb  = m0 >> 11;        // batch
    const int jj0 = m0 & 2047;       // j within batch (block never crosses batch)
    for (int pass = 0; pass < 2; pass++) {
        #pragma unroll
        for (int mt = 0; mt < 4; mt++)
            #pragma unroll
            for (int nt = 0; nt < 2; nt++) {
                const int nl = wc*32 + nt*16 + lr;
                const int ml = wr*64 + mt*16 + lk*4;
                const float vv[4] = {acc[mt][nt].x, acc[mt][nt].y, acc[mt][nt].z, acc[mt][nt].w};
                unsigned short s[4];
                #pragma unroll
                for (int r = 0; r < 4; r++) {
                    const unsigned short hh = f2bf(vv[r]);
                    s[r] = pass ? f2bf(vv[r] - bf2f(hh)) : hh;
                }
                *(unsigned*)&Tr[nl][ml]     = s[0] | ((unsigned)s[1] << 16);
                *(unsigned*)&Tr[nl][ml + 2] = s[2] | ((unsigned)s[3] << 16);
            }
        __syncthreads();
        unsigned short* dst = pass ? ht_lo : ht_hi;
        #pragma unroll
        for (int q = 0; q < 4; q++) {
            const int idx = t + 256*q, row = idx >> 4, c = idx & 15;
            *(uint4*)(dst + ((size_t)(bb * FOUT + n0 + row)) * NN + jj0 + c*8) =
                *(const uint4*)&Tr[row][c*8];
        }
        __syncthreads();   // pass-1 writes must wait for pass-0 reads
    }
}

// ---------------------------------------------------------------------------
// Kernel 2: f = h@a1, g = h@a2 from split ht.
// ---------------------------------------------------------------------------
__global__ __launch_bounds__(256) void fg2(const unsigned short* __restrict__ ht_hi,
                                           const unsigned short* __restrict__ ht_lo,
                                           const float* __restrict__ a,
                                           float* __restrict__ f, float* __restrict__ g) {
    const int lane  = threadIdx.x & 63;
    const int chunk = blockIdx.x * 4 + (threadIdx.x >> 6);
    const int b  = chunk >> 5;
    const int jw = (chunk & 31) * 64 + lane;
    const size_t base = (size_t)b * FOUT * NN + jw;
    float fs = 0.f, gs = 0.f;
    #pragma unroll 4
    for (int n = 0; n < FOUT; n++) {
        const float hv = bf2f(ht_hi[base + (size_t)n * NN]) + bf2f(ht_lo[base + (size_t)n * NN]);
        fs = fmaf(hv, a[n], fs);
        gs = fmaf(hv, a[FOUT + n], gs);
    }
    f[b * NN + jw] = fs;
    g[b * NN + jw] = gs;
}

// ---------------------------------------------------------------------------
// Kernel 3: fused attention. 512 threads = 8 waves (2/SIMD), 64 i-rows x 256 n.
// Wave = 32i x 64n (wr2 x wc4). KVBLK=64. LDS 82.7KB, linear LDS dest + XOR
// chunk swizzle via inverse-swizzled per-lane GLOBAL source (rule #21).
// adj AND g for tile jt+1 prefetched into regs during MFMA phase, so phase A
// is pure-VALU and fully overlaps the async global_load_lds staging (vmcnt
// FIFO: any VMEM use in phase A would drain the staging queue early).
// ---------------------------------------------------------------------------
__global__ __launch_bounds__(512, 1) void gat_attn(
        const unsigned short* __restrict__ ht_hi,
        const unsigned short* __restrict__ ht_lo,
        const int* __restrict__ adj,
        const float* __restrict__ f, const float* __restrict__ g,
        float* __restrict__ out) {
    __shared__ __attribute__((aligned(16))) unsigned short Hs_hi[256*64];
    __shared__ __attribute__((aligned(16))) unsigned short Hs_lo[256*64];
    __shared__ __attribute__((aligned(16))) unsigned short Ps_hi[64*64];
    __shared__ __attribute__((aligned(16))) unsigned short Ps_lo[64*64];
    __shared__ __attribute__((aligned(16))) float m_s[64];
    __shared__ __attribute__((aligned(16))) float l_s[64];
    __shared__ __attribute__((aligned(16))) float fac_s[64];

    const int b  = blockIdx.x & 7;
    const int i0 = (blockIdx.x >> 3) * 64;
    const int t  = threadIdx.x;
    const int w  = t >> 6, l = t & 63;
    const int lr = l & 15, lk = l >> 4;
    const int wr = w >> 2, wc = w & 3;      // 2 i-halves x 4 n-quarters
    const int ar = t >> 3, jg = t & 7;      // phase A: row, j-octet

    const float fi = f[b * NN + i0 + ar];
    if (t < 64) { m_s[t] = -INFINITY; l_s[t] = 0.f; }

    f32x4 acc[2][4];
    #pragma unroll
    for (int mt = 0; mt < 2; mt++)
        #pragma unroll
        for (int nt = 0; nt < 4; nt++) acc[mt][nt] = (f32x4){0.f,0.f,0.f,0.f};

    const unsigned short* hb_hi = ht_hi + (size_t)b * FOUT * NN;
    const unsigned short* hb_lo = ht_lo + (size_t)b * FOUT * NN;
    const size_t arow = ((size_t)b * NN + i0 + ar) * NN + jg * 8;
    const float* grow = g + b * NN + jg * 8;

    // prefetch tile 0 operands into registers
    int4   adjA = *(const int4*)(adj + arow);
    int4   adjB = *(const int4*)(adj + arow + 4);
    float4 gA   = *(const float4*)(grow);
    float4 gB   = *(const float4*)(grow + 4);

    const int sidx = w * 4;   // staging: 4 wave-insts per wave per array

    for (int jt = 0; jt < 32; jt++) {
        __syncthreads();   // prev phase B done with Hs/Ps; init visible (tile 0)

        // ---- stage: async global->LDS, inverse-swizzled global source ----
        const int j0 = jt * 64;
        #pragma unroll
        for (int q = 0; q < 4; q++) {
            const int idx = (sidx + q) * 64 + l;
            const int n = idx >> 3, c = idx & 7;
            const int cc = c ^ (n & 7);
            const size_t go = (size_t)n * NN + j0 + cc * 8;
            gload_lds16(hb_hi + go, &Hs_hi[(sidx + q) * 512]);
            gload_lds16(hb_lo + go, &Hs_lo[(sidx + q) * 512]);
        }

        // ---- phase A (pure VALU): scores + online softmax + P split-bf16 ----
        {
            float s[8];
            {
                const float v0 = fi + gA.x, v1 = fi + gA.y, v2 = fi + gA.z, v3 = fi + gA.w;
                const float v4 = fi + gB.x, v5 = fi + gB.y, v6 = fi + gB.z, v7 = fi + gB.w;
                s[0] = adjA.x > 0 ? (v0 > 0.f ? v0 : 0.2f*v0) : NEG_BIG;
                s[1] = adjA.y > 0 ? (v1 > 0.f ? v1 : 0.2f*v1) : NEG_BIG;
                s[2] = adjA.z > 0 ? (v2 > 0.f ? v2 : 0.2f*v2) : NEG_BIG;
                s[3] = adjA.w > 0 ? (v3 > 0.f ? v3 : 0.2f*v3) : NEG_BIG;
                s[4] = adjB.x > 0 ? (v4 > 0.f ? v4 : 0.2f*v4) : NEG_BIG;
                s[5] = adjB.y > 0 ? (v5 > 0.f ? v5 : 0.2f*v5) : NEG_BIG;
                s[6] = adjB.z > 0 ? (v6 > 0.f ? v6 : 0.2f*v6) : NEG_BIG;
                s[7] = adjB.w > 0 ? (v7 > 0.f ? v7 : 0.2f*v7) : NEG_BIG;
            }
            float mloc = s[0];
            #pragma unroll
            for (int e = 1; e < 8; e++) mloc = fmaxf(mloc, s[e]);
            mloc = fmaxf(mloc, __shfl_xor(mloc, 1));
            mloc = fmaxf(mloc, __shfl_xor(mloc, 2));
            mloc = fmaxf(mloc, __shfl_xor(mloc, 4));
            const float m_old = m_s[ar];            // 8-lane group, same wave
            const float m_new = fmaxf(m_old, mloc);
            float p[8], rs = 0.f;
            #pragma unroll
            for (int e = 0; e < 8; e++) { p[e] = __expf(s[e] - m_new); rs += p[e]; }
            rs += __shfl_xor(rs, 1);
            rs += __shfl_xor(rs, 2);
            rs += __shfl_xor(rs, 4);
            if (jg == 0) {
                const float fac = __expf(m_old - m_new);   // 0 on first tile
                fac_s[ar] = fac;
                l_s[ar]   = l_s[ar] * fac + rs;
                m_s[ar]   = m_new;
            }
            unsigned ph[4], pl[4];
            #pragma unroll
            for (int e = 0; e < 8; e += 2) {
                const unsigned short h0 = f2bf(p[e]),   h1 = f2bf(p[e+1]);
                const unsigned short q0 = f2bf(p[e] - bf2f(h0));
                const unsigned short q1 = f2bf(p[e+1] - bf2f(h1));
                ph[e >> 1] = h0 | ((unsigned)h1 << 16);
                pl[e >> 1] = q0 | ((unsigned)q1 << 16);
            }
            const int cs = (jg ^ (ar & 7)) * 8;
            *(uint4*)&Ps_hi[ar * 64 + cs] = make_uint4(ph[0], ph[1], ph[2], ph[3]);
            *(uint4*)&Ps_lo[ar * 64 + cs] = make_uint4(pl[0], pl[1], pl[2], pl[3]);
        }
        __syncthreads();   // Hs (vmcnt drained by barrier), Ps, fac ready

        // ---- prefetch adj+g for next tile (lands during MFMA) ----
        if (jt + 1 < 32) {
            const size_t o = (size_t)(jt + 1) * 64;
            adjA = *(const int4*)(adj + arow + o);
            adjB = *(const int4*)(adj + arow + o + 4);
            gA   = *(const float4*)(grow + o);
            gB   = *(const float4*)(grow + o + 4);
        }

        // ---- phase B: rescale + MFMA PV (3-product split) ----
        #pragma unroll
        for (int mt = 0; mt < 2; mt++) {
            const f32x4 fac4 = *(const f32x4*)&fac_s[wr*32 + mt*16 + lk*4];
            #pragma unroll
            for (int nt = 0; nt < 4; nt++) acc[mt][nt] *= fac4;
        }
        #pragma unroll
        for (int kt = 0; kt < 2; kt++) {
            bf16x8 ah[2], al[2], bh[4], bl[4];
            #pragma unroll
            for (int mt = 0; mt < 2; mt++) {
                const int row = wr*32 + mt*16 + lr;
                const int cs  = ((kt*4 + lk) ^ (row & 7)) * 8;
                ah[mt] = *(const bf16x8*)&Ps_hi[row * 64 + cs];
                al[mt] = *(const bf16x8*)&Ps_lo[row * 64 + cs];
            }
            #pragma unroll
            for (int nt = 0; nt < 4; nt++) {
                const int n  = wc*64 + nt*16 + lr;
                const int cs = ((kt*4 + lk) ^ (n & 7)) * 8;
                bh[nt] = *(const bf16x8*)&Hs_hi[n * 64 + cs];
                bl[nt] = *(const bf16x8*)&Hs_lo[n * 64 + cs];
            }
            #pragma unroll
            for (int nt = 0; nt < 4; nt++)
                #pragma unroll
                for (int mt = 0; mt < 2; mt++)
                    acc[mt][nt] = __builtin_amdgcn_mfma_f32_16x16x32_bf16(ah[mt], bh[nt], acc[mt][nt], 0, 0, 0);
            #pragma unroll
            for (int nt = 0; nt < 4; nt++)
                #pragma unroll
                for (int mt = 0; mt < 2; mt++)
                    acc[mt][nt] = __builtin_amdgcn_mfma_f32_16x16x32_bf16(ah[mt], bl[nt], acc[mt][nt], 0, 0, 0);
            #pragma unroll
            for (int nt = 0; nt < 4; nt++)
                #pragma unroll
                for (int mt = 0; mt < 2; mt++)
                    acc[mt][nt] = __builtin_amdgcn_mfma_f32_16x16x32_bf16(al[mt], bh[nt], acc[mt][nt], 0, 0, 0);
        }
    }

    __syncthreads();   // l_s final, cross-wave
    #pragma unroll
    for (int mt = 0; mt < 2; mt++) {
        const f32x4 lv = *(const f32x4*)&l_s[wr*32 + mt*16 + lk*4];
        const float linv[4] = {1.f/lv.x, 1.f/lv.y, 1.f/lv.z, 1.f/lv.w};
        #pragma unroll
        for (int nt = 0; nt < 4; nt++) {
            const int n = wc*64 + nt*16 + lr;
            const float av[4] = {acc[mt][nt].x, acc[mt][nt].y, acc[mt][nt].z, acc[mt][nt].w};
            #pragma unroll
            for (int r = 0; r < 4; r++) {
                float v = av[r] * linv[r];
                v = v > 0.f ? v : (__expf(v) - 1.f);
                out[((size_t)(b * NN + i0 + wr*32 + mt*16 + lk*4 + r)) * FOUT + n] = v;
            }
        }
    }
}

// ---------------------------------------------------------------------------
extern "C" void kernel_launch(void* const* d_in, const int* in_sizes, int n_in,
                              void* d_out, int out_size, void* d_ws, size_t ws_size,
                              hipStream_t stream) {
    const float* x   = (const float*)d_in[0];   // (8, 2048, 512)
    const int*   adj = (const int*)  d_in[1];   // (8, 2048, 2048)
    const float* W   = (const float*)d_in[2];   // (512, 256)
    const float* a   = (const float*)d_in[3];   // (512, 1)
    float* outp = (float*)d_out;                // (8, 2048, 256) fp32

    char* ws = (char*)d_ws;
    unsigned short* ht_hi = (unsigned short*)ws;                       ws += (size_t)BATCH*FOUT*NN*2;
    unsigned short* ht_lo = (unsigned short*)ws;                       ws += (size_t)BATCH*FOUT*NN*2;
    unsigned short* Wt_hi = (unsigned short*)ws;                       ws += (size_t)FOUT*FIN*2;
    unsigned short* Wt_lo = (unsigned short*)ws;                       ws += (size_t)FOUT*FIN*2;
    float* f = (float*)ws;                                             ws += (size_t)BATCH*NN*4;
    float* g = (float*)ws;

    wt_prep <<<128, 256, 0, stream>>>(W, Wt_hi, Wt_lo);
    gemm_xw <<<512, 256, 0, stream>>>(x, Wt_hi, Wt_lo, ht_hi, ht_lo);
    fg2     <<<64,  256, 0, stream>>>(ht_hi, ht_lo, a, f, g);
    gat_attn<<<256, 512, 0, stream>>>(ht_hi, ht_lo, adj, f, g, outp);
}